// Round 9
// baseline (137.949 us; speedup 1.0000x reference)
//
#include <hip/hip_runtime.h>
#include <hip/hip_bf16.h>

typedef __attribute__((ext_vector_type(8))) short short8;
typedef __attribute__((ext_vector_type(4))) float f32x4;

#define H_DIM 768
#define E_EXP 16
#define T_TASK 8
#define KSEL 4
#define L_SEQ 8192
#define B_BATCH 16
#define EW_STRIDE (768*768)

#define CVT_BLOCKS 3072    // (8192*768/8)/256 uint4 stores
#define WCT_BLOCKS 576     // 24 x 24 tiles of 32x32
#define FILL1_BLOCKS 1408  // batches 1..8 (201.3 MB)
#define GEMM_BLOCKS 1536   // 128 m x 12 n tiles of 64x64 -> 6 blocks/CU
#define FILL2_BLOCKS 2048  // batches 9..15 (176.2 MB)

// ------------------------------------------------------------------ K1 ------
// (identical to the 119us round-5 kernel)
__global__ __launch_bounds__(256) void k1_cvt_wct_fill(
    const float4* __restrict__ x,
    const float* __restrict__ task_full,
    const float* __restrict__ gate_w,
    const float* __restrict__ gate_b,
    const float* __restrict__ expert_w,
    __hip_bfloat16* __restrict__ wct,
    uint4* __restrict__ xb,
    float* __restrict__ out_tail,
    float4* __restrict__ fill_p, size_t fill_n4) {
  const int bid = blockIdx.x;
  const int tid = threadIdx.x;
  if (bid < CVT_BLOCKS) {
    const int i = bid * 256 + tid;  // one uint4 = 8 bf16
    const float4 a = x[2 * i];
    const float4 b = x[2 * i + 1];
    alignas(16) __hip_bfloat16 h[8];
    h[0] = __float2bfloat16(a.x); h[1] = __float2bfloat16(a.y);
    h[2] = __float2bfloat16(a.z); h[3] = __float2bfloat16(a.w);
    h[4] = __float2bfloat16(b.x); h[5] = __float2bfloat16(b.y);
    h[6] = __float2bfloat16(b.z); h[7] = __float2bfloat16(b.w);
    xb[i] = *(const uint4*)h;
  } else if (bid < CVT_BLOCKS + WCT_BLOCKS) {
    __shared__ float silu_s[T_TASK * H_DIM];
    __shared__ float logits[T_TASK][E_EXP];
    __shared__ float g_sh[KSEL];
    __shared__ int   i_sh[KSEL];
    __shared__ float tile[32][33];
    const int wb = bid - CVT_BLOCKS;
    for (int i = tid; i < T_TASK * H_DIM; i += 256) {
      float v = task_full[i];
      silu_s[i] = v / (1.f + expf(-v));
    }
    __syncthreads();
    if (tid < T_TASK * E_EXP) {
      const int t = tid >> 4, e = tid & 15;
      float a0 = 0.f, a1 = 0.f, a2 = 0.f, a3 = 0.f;
      const float* sl = &silu_s[t * H_DIM];
      for (int h = 0; h < H_DIM; h += 4) {
        a0 += sl[h]     * gate_w[(h)     * E_EXP + e];
        a1 += sl[h + 1] * gate_w[(h + 1) * E_EXP + e];
        a2 += sl[h + 2] * gate_w[(h + 2) * E_EXP + e];
        a3 += sl[h + 3] * gate_w[(h + 3) * E_EXP + e];
      }
      logits[t][e] = (a0 + a1) + (a2 + a3) + gate_b[e];
    }
    __syncthreads();
    if (tid < T_TASK) {
      const int t = tid;
      float p[E_EXP];
      float m = -1e30f;
      for (int e = 0; e < E_EXP; ++e) m = fmaxf(m, logits[t][e]);
      float s = 0.f;
      for (int e = 0; e < E_EXP; ++e) { p[e] = expf(logits[t][e] - m); s += p[e]; }
      const float inv = 1.f / s;
      for (int e = 0; e < E_EXP; ++e) p[e] *= inv;
      bool used[E_EXP];
      for (int e = 0; e < E_EXP; ++e) used[e] = false;
      float g[KSEL]; int sel[KSEL];
      for (int k = 0; k < KSEL; ++k) {
        float bv = -1.f; int bi = 0;
        for (int e = 0; e < E_EXP; ++e)
          if (!used[e] && p[e] > bv) { bv = p[e]; bi = e; }
        used[bi] = true; sel[k] = bi; g[k] = bv;
      }
      if (wb == 0) {
        for (int e = 0; e < E_EXP; ++e)
          out_tail[E_EXP + t * E_EXP + e] = used[e] ? 1.f : 0.f;
        if (t == 0)
          for (int e = 0; e < E_EXP; ++e) out_tail[e] = p[e];
      }
      if (t == 0)
        for (int k = 0; k < KSEL; ++k) { g_sh[k] = g[k]; i_sh[k] = sel[k]; }
    }
    __syncthreads();
    const float g0 = g_sh[0], g1 = g_sh[1], g2 = g_sh[2], g3 = g_sh[3];
    const size_t e0 = (size_t)i_sh[0] * EW_STRIDE;
    const size_t e1 = (size_t)i_sh[1] * EW_STRIDE;
    const size_t e2 = (size_t)i_sh[2] * EW_STRIDE;
    const size_t e3 = (size_t)i_sh[3] * EW_STRIDE;
    const int d0 = (wb % 24) * 32, o0 = (wb / 24) * 32;
    const int c = tid & 31;
    const int r0 = tid >> 5;  // 0..7
#pragma unroll
    for (int it = 0; it < 4; ++it) {
      const int rr = it * 8 + r0;  // d offset
      const size_t off = (size_t)(d0 + rr) * H_DIM + o0 + c;
      tile[rr][c] = g0 * expert_w[e0 + off] + g1 * expert_w[e1 + off] +
                    g2 * expert_w[e2 + off] + g3 * expert_w[e3 + off];
    }
    __syncthreads();
#pragma unroll
    for (int it = 0; it < 4; ++it) {
      const int rr = it * 8 + r0;  // o offset
      wct[(size_t)(o0 + rr) * H_DIM + d0 + c] = __float2bfloat16(tile[c][rr]);
    }
  } else {
    const int fb = bid - CVT_BLOCKS - WCT_BLOCKS;
    size_t i = (size_t)fb * 256 + tid;
    const size_t stride = (size_t)FILL1_BLOCKS * 256;
    const float4 one = make_float4(1.f, 1.f, 1.f, 1.f);
    for (; i < fill_n4; i += stride) fill_p[i] = one;
  }
}

// ------------------------------------------------------------------ K2 ------
__device__ __forceinline__ void gload_lds16(const void* g, void* l) {
  __builtin_amdgcn_global_load_lds((const __attribute__((address_space(1))) void*)g,
                                   (__attribute__((address_space(3))) void*)l, 16, 0, 0);
}

// GEMM only: C[l][o] = 1 + sum_d A[l][d]*Bt[o][d]. 64x64 tiles -> 1536 blocks
// (6/CU): six independent barrier-chains per CU overlap the per-step drains.
__global__ __launch_bounds__(256) void k2_gemm(
    const __hip_bfloat16* __restrict__ A,      // x0 bf16 [8192][768]
    const __hip_bfloat16* __restrict__ Bt,     // wct [768][768] o-major
    float* __restrict__ C) {
  __shared__ __hip_bfloat16 As[64 * 32];
  __shared__ __hip_bfloat16 Bs[64 * 32];
  const int bid = blockIdx.x;
  const int tid = threadIdx.x;
  const int m0 = (bid / 12) * 64;
  const int n0 = (bid % 12) * 64;
  const int lane = tid & 63;
  const int w = tid >> 6;
  const int wr = w >> 1, wc = w & 1;      // 2x2 waves, 32x32 output each
  const int r = tid >> 2, s = tid & 3;    // staging: row 0..63, 16B chunk
  const __hip_bfloat16* ga = A  + (size_t)(m0 + r) * H_DIM + s * 8;
  const __hip_bfloat16* gb = Bt + (size_t)(n0 + r) * H_DIM + s * 8;
  f32x4 acc[2][2] = {};
  const int arow = wr * 32 + (lane & 15);
  const int brow = wc * 32 + (lane & 15);
  const int koff = (lane >> 4) * 8;  // same k map for A and B -> k-perm safe
  for (int k0 = 0; k0 < H_DIM; k0 += 32) {
    gload_lds16(ga + k0, &As[tid * 8]);
    gload_lds16(gb + k0, &Bs[tid * 8]);
    __syncthreads();
    short8 av[2], bv[2];
#pragma unroll
    for (int i = 0; i < 2; ++i) av[i] = *(const short8*)&As[(arow + i * 16) * 32 + koff];
#pragma unroll
    for (int j = 0; j < 2; ++j) bv[j] = *(const short8*)&Bs[(brow + j * 16) * 32 + koff];
#pragma unroll
    for (int i = 0; i < 2; ++i)
#pragma unroll
      for (int j = 0; j < 2; ++j)
        acc[i][j] = __builtin_amdgcn_mfma_f32_16x16x32_bf16(av[i], bv[j], acc[i][j], 0, 0, 0);
    __syncthreads();
  }
  const int crow0 = m0 + wr * 32 + (lane >> 4) * 4;
  const int ccol0 = n0 + wc * 32 + (lane & 15);
#pragma unroll
  for (int i = 0; i < 2; ++i)
#pragma unroll
    for (int j = 0; j < 2; ++j)
#pragma unroll
      for (int q = 0; q < 4; ++q)
        C[(size_t)(crow0 + i * 16 + q) * H_DIM + ccol0 + j * 16] = 1.0f + acc[i][j][q];
}

// ------------------------------------------------------------------ K3 ------
__global__ __launch_bounds__(256) void k3_fill(float4* __restrict__ p, size_t n4) {
  size_t i = (size_t)blockIdx.x * 256 + threadIdx.x;
  const size_t stride = (size_t)FILL2_BLOCKS * 256;
  const float4 one = make_float4(1.f, 1.f, 1.f, 1.f);
  for (; i < n4; i += stride) p[i] = one;
}

// ---------------------------------------------------------------- launch ----
extern "C" void kernel_launch(void* const* d_in, const int* in_sizes, int n_in,
                              void* d_out, int out_size, void* d_ws, size_t ws_size,
                              hipStream_t stream) {
  const float* x         = (const float*)d_in[0];  // [16][8192][768]
  const float* task_full = (const float*)d_in[1];  // [8][768]
  const float* gate_w    = (const float*)d_in[2];  // [768][16]
  const float* gate_b    = (const float*)d_in[3];  // [16]
  const float* expert_w  = (const float*)d_in[4];  // [16][768][768]
  float* out = (float*)d_out;

  const size_t n_out_main = (size_t)B_BATCH * L_SEQ * H_DIM;  // 100663296
  float* out_tail = out + n_out_main;

  __hip_bfloat16* wct = (__hip_bfloat16*)d_ws;                          // 1.18 MB
  __hip_bfloat16* x0b = (__hip_bfloat16*)((char*)d_ws + (size_t)EW_STRIDE * 2);

  // K1: x0->bf16 | inline-gating + wct | fill batches 1..8
  const size_t fill1_n4 = (size_t)8 * L_SEQ * H_DIM / 4;
  k1_cvt_wct_fill<<<CVT_BLOCKS + WCT_BLOCKS + FILL1_BLOCKS, 256, 0, stream>>>(
      (const float4*)x, task_full, gate_w, gate_b, expert_w,
      wct, (uint4*)x0b, out_tail,
      (float4*)(out + (size_t)L_SEQ * H_DIM), fill1_n4);

  // K2: GEMM only (64x64 tiles, 6 blocks/CU) -> out[0] with +1.0
  k2_gemm<<<GEMM_BLOCKS, 256, 0, stream>>>(x0b, wct, out);

  // K3: fill batches 9..15
  const size_t fill2_n4 = (size_t)7 * L_SEQ * H_DIM / 4;
  k3_fill<<<FILL2_BLOCKS, 256, 0, stream>>>(
      (float4*)(out + (size_t)9 * L_SEQ * H_DIM), fill2_n4);
}